// Round 1
// baseline (466.281 us; speedup 1.0000x reference)
//
#include <hip/hip_runtime.h>
#include <hip/hip_bf16.h>
#include <stdint.h>

#define NNODES 100000
#define HID 128
#define TSZ 32
#define MDIM 16
#define ES 600000
#define ED 600000
#define ETOT (ES + ED)
#define GN (2 * NNODES)     // both branches share one node index space
#define GNP 200704          // 196 * 1024, padded for the scan
#define SCAN_BLOCKS 196
#define N16 (NNODES * MDIM) // 1,600,000

typedef unsigned short ushort_t;

__device__ __forceinline__ float bflo(unsigned u) { return __uint_as_float(u << 16); }
__device__ __forceinline__ float bfhi(unsigned u) { return __uint_as_float(u & 0xffff0000u); }

__device__ __forceinline__ float tanh_fast(float v) {
    float z = __expf(2.f * v);          // z in [0, inf]
    return 1.f - 2.f / (z + 1.f);       // z=inf -> 1, z=0 -> -1
}

// ---------------------------------------------------------------- init
// m_a[0:N16] = mask (spatial), m_a[N16:2*N16] = mask (dom); counts = 0
__global__ void k_init(const float* __restrict__ mask, float* __restrict__ m_a,
                       int* __restrict__ counts) {
    int idx = blockIdx.x * 256 + threadIdx.x;
    if (idx < N16) {
        float v = mask[idx];
        m_a[idx] = v;
        m_a[N16 + idx] = v;
    }
    if (idx < GNP) counts[idx] = 0;
}

// ---------------------------------------------------------------- PQ = [x@Wsrc + b, x@Wdst]  (bf16 out)
// block = 64 threads (one per output column), 8 nodes per block.
// x reads are wave-uniform -> scalar loads; W reads are L1-hot.
__global__ __launch_bounds__(64) void k_pq(const float* __restrict__ x,
                                           const float* __restrict__ Wt,
                                           const float* __restrict__ bt,
                                           __hip_bfloat16* __restrict__ pq) {
    const int t = threadIdx.x;             // 0..63
    const int n0 = blockIdx.x * 8;
    const float* wcol = (t < 32) ? (Wt + t) : (Wt + 128 * 32 + (t - 32));
    float acc[8] = {0.f, 0.f, 0.f, 0.f, 0.f, 0.f, 0.f, 0.f};
#pragma unroll 4
    for (int h = 0; h < 128; ++h) {
        float wv = wcol[h * 32];
#pragma unroll
        for (int j = 0; j < 8; ++j)
            acc[j] = fmaf(x[(n0 + j) * 128 + h], wv, acc[j]);
    }
    float bv = (t < 32) ? bt[t] : 0.f;
#pragma unroll
    for (int j = 0; j < 8; ++j)
        pq[(n0 + j) * 64 + t] = __float2bfloat16(acc[j] + bv);
}

// ---------------------------------------------------------------- in-degree counts
__global__ void k_count(const int* __restrict__ sdst, const int* __restrict__ ddst,
                        int* __restrict__ counts) {
    int e = blockIdx.x * 256 + threadIdx.x;
    if (e >= ETOT) return;
    int gd = (e < ES) ? sdst[e] : (ddst[e - ES] + NNODES);
    atomicAdd(&counts[gd], 1);
}

// ---------------------------------------------------------------- scan (3 kernels)
__global__ __launch_bounds__(256) void k_scan1(const int* __restrict__ counts,
                                               int* __restrict__ bsum) {
    __shared__ int sh[256];
    int tid = threadIdx.x;
    int4 v = ((const int4*)counts)[blockIdx.x * 256 + tid];
    sh[tid] = v.x + v.y + v.z + v.w;
    __syncthreads();
    for (int o = 128; o > 0; o >>= 1) {
        if (tid < o) sh[tid] += sh[tid + o];
        __syncthreads();
    }
    if (tid == 0) bsum[blockIdx.x] = sh[0];
}

__global__ __launch_bounds__(256) void k_scan2(const int* __restrict__ bsum,
                                               int* __restrict__ prefix) {
    __shared__ int sh[256];
    int tid = threadIdx.x;
    int v = (tid < SCAN_BLOCKS) ? bsum[tid] : 0;
    sh[tid] = v;
    __syncthreads();
    for (int o = 1; o < 256; o <<= 1) {
        int add = (tid >= o) ? sh[tid - o] : 0;
        __syncthreads();
        sh[tid] += add;
        __syncthreads();
    }
    prefix[tid] = sh[tid] - v; // exclusive
}

__global__ __launch_bounds__(256) void k_scan3(const int* __restrict__ counts,
                                               const int* __restrict__ prefix,
                                               int* __restrict__ off,
                                               int* __restrict__ cursor) {
    __shared__ int sh[256];
    int tid = threadIdx.x;
    int4 v = ((const int4*)counts)[blockIdx.x * 256 + tid];
    int tot = v.x + v.y + v.z + v.w;
    sh[tid] = tot;
    __syncthreads();
    for (int o = 1; o < 256; o <<= 1) {
        int add = (tid >= o) ? sh[tid - o] : 0;
        __syncthreads();
        sh[tid] += add;
        __syncthreads();
    }
    int excl = sh[tid] - tot + prefix[blockIdx.x];
    int4 o4;
    o4.x = excl;
    o4.y = o4.x + v.x;
    o4.z = o4.y + v.y;
    o4.w = o4.z + v.z;
    ((int4*)off)[blockIdx.x * 256 + tid] = o4;
    ((int4*)cursor)[blockIdx.x * 256 + tid] = o4;
}

// ---------------------------------------------------------------- ew + CSR fill
// per edge: ew = sigmoid(attr@Wa + sum_t tanh(P[src][t]+Q[dst][t]) * Wt[t] + b)
// then csr[atomicAdd(cursor[dst_g])] = {src_g, ew_bits}
__global__ void k_ewfill(const ushort_t* __restrict__ pq,
                         const int* __restrict__ ssrc, const int* __restrict__ sdst,
                         const int* __restrict__ dsrc, const int* __restrict__ ddst,
                         const float* __restrict__ sattr, const float* __restrict__ dattr,
                         const float* __restrict__ Wp, const float* __restrict__ bp,
                         const float* __restrict__ Wd, const float* __restrict__ bd,
                         int* __restrict__ cursor, int2* __restrict__ csr) {
    int e = blockIdx.x * 256 + threadIdx.x;
    if (e >= ETOT) return;
    int src, dstg, srcg;
    float acc;
    const float* wt;
    if (e < ES) {
        src = ssrc[e];
        int dst = sdst[e];
        dstg = dst;
        srcg = src;
        const float4 a = *(const float4*)(sattr + (size_t)e * 4);
        acc = bp[0] + a.x * Wp[0] + a.y * Wp[1] + a.z * Wp[2] + a.w * Wp[3];
        wt = Wp + 4;
        // P from src, Q from dst
        const uint4* Pp = (const uint4*)(pq + (size_t)src * 64);
        const uint4* Qp = (const uint4*)(pq + (size_t)dst * 64 + 32);
#pragma unroll
        for (int c = 0; c < 4; ++c) {
            uint4 pu = Pp[c], qu = Qp[c];
            unsigned pw[4] = {pu.x, pu.y, pu.z, pu.w};
            unsigned qw[4] = {qu.x, qu.y, qu.z, qu.w};
#pragma unroll
            for (int k = 0; k < 4; ++k) {
                float v0 = bflo(pw[k]) + bflo(qw[k]);
                float v1 = bfhi(pw[k]) + bfhi(qw[k]);
                int t = c * 8 + k * 2;
                acc = fmaf(tanh_fast(v0), wt[t], acc);
                acc = fmaf(tanh_fast(v1), wt[t + 1], acc);
            }
        }
    } else {
        int ed = e - ES;
        src = dsrc[ed];
        int dst = ddst[ed];
        dstg = dst + NNODES;
        srcg = src + NNODES;
        acc = bd[0] + dattr[ed] * Wd[0];
        wt = Wd + 1;
        const uint4* Pp = (const uint4*)(pq + (size_t)src * 64);
        const uint4* Qp = (const uint4*)(pq + (size_t)dst * 64 + 32);
#pragma unroll
        for (int c = 0; c < 4; ++c) {
            uint4 pu = Pp[c], qu = Qp[c];
            unsigned pw[4] = {pu.x, pu.y, pu.z, pu.w};
            unsigned qw[4] = {qu.x, qu.y, qu.z, qu.w};
#pragma unroll
            for (int k = 0; k < 4; ++k) {
                float v0 = bflo(pw[k]) + bflo(qw[k]);
                float v1 = bfhi(pw[k]) + bfhi(qw[k]);
                int t = c * 8 + k * 2;
                acc = fmaf(tanh_fast(v0), wt[t], acc);
                acc = fmaf(tanh_fast(v1), wt[t + 1], acc);
            }
        }
    }
    float ew = 1.f / (1.f + __expf(-acc));
    int pos = atomicAdd(&cursor[dstg], 1);
    csr[pos] = make_int2(srcg, __float_as_int(ew));
}

// ---------------------------------------------------------------- one propagation round (gather, no atomics)
// thread = (global node g, mask dim j). m_out[g,j] = max(m_in[g,j], max over in-edges m_in[src,j]*ew)
__global__ void k_round(const float* __restrict__ m_in, float* __restrict__ m_out,
                        const int* __restrict__ off, const int2* __restrict__ csr) {
    int idx = blockIdx.x * 256 + threadIdx.x;
    if (idx >= GN * MDIM) return;
    int g = idx >> 4;
    int j = idx & 15;
    int p0 = off[g], p1 = off[g + 1];
    float vmax = m_in[idx];
    for (int p = p0; p < p1; ++p) {
        int2 en = csr[p];
        float v = m_in[(en.x << 4) + j] * __int_as_float(en.y);
        vmax = fmaxf(vmax, v);
    }
    m_out[idx] = vmax;
}

// ---------------------------------------------------------------- final combine
__global__ void k_combine(const float* __restrict__ m, float* __restrict__ out) {
    int idx = blockIdx.x * 256 + threadIdx.x;
    if (idx < N16) out[idx] = fmaxf(m[idx], m[N16 + idx]);
}

extern "C" void kernel_launch(void* const* d_in, const int* in_sizes, int n_in,
                              void* d_out, int out_size, void* d_ws, size_t ws_size,
                              hipStream_t stream) {
    const float* x     = (const float*)d_in[0];
    const float* mask  = (const float*)d_in[1];
    const int*   sei   = (const int*)d_in[2];
    const int*   dei   = (const int*)d_in[3];
    const float* sattr = (const float*)d_in[4];
    const float* dattr = (const float*)d_in[5];
    const float* Wt    = (const float*)d_in[6];
    const float* bt    = (const float*)d_in[7];
    const float* Wp    = (const float*)d_in[8];
    const float* bp    = (const float*)d_in[9];
    const float* Wd    = (const float*)d_in[10];
    const float* bd    = (const float*)d_in[11];
    float* out = (float*)d_out;

    char* ws = (char*)d_ws;
    size_t o = 0;
    auto take = [&](size_t bytes) -> char* {
        char* p = ws + o;
        o = (o + bytes + 255) & ~(size_t)255;
        return p;
    };
    __hip_bfloat16* pq = (__hip_bfloat16*)take((size_t)NNODES * 64 * 2);
    int* counts = (int*)take((size_t)GNP * 4);
    int* off    = (int*)take((size_t)GNP * 4);
    int* cursor = (int*)take((size_t)GNP * 4);
    int* bsum   = (int*)take(256 * 4);
    int* prefix = (int*)take(256 * 4);
    int2* csr   = (int2*)take((size_t)ETOT * 8);
    float* m_a  = (float*)take((size_t)2 * N16 * 4);
    float* m_b  = (float*)take((size_t)2 * N16 * 4);

    k_init<<<6250, 256, 0, stream>>>(mask, m_a, counts);
    k_pq<<<12500, 64, 0, stream>>>(x, Wt, bt, pq);
    k_count<<<(ETOT + 255) / 256, 256, 0, stream>>>(sei + ES, dei + ED, counts);
    k_scan1<<<SCAN_BLOCKS, 256, 0, stream>>>(counts, bsum);
    k_scan2<<<1, 256, 0, stream>>>(bsum, prefix);
    k_scan3<<<SCAN_BLOCKS, 256, 0, stream>>>(counts, prefix, off, cursor);
    k_ewfill<<<(ETOT + 255) / 256, 256, 0, stream>>>((const ushort_t*)pq,
        sei, sei + ES, dei, dei + ED, sattr, dattr, Wp, bp, Wd, bd, cursor, csr);
    k_round<<<(GN * MDIM) / 256, 256, 0, stream>>>(m_a, m_b, off, csr);
    k_round<<<(GN * MDIM) / 256, 256, 0, stream>>>(m_b, m_a, off, csr);
    k_round<<<(GN * MDIM) / 256, 256, 0, stream>>>(m_a, m_b, off, csr);
    k_combine<<<(N16 + 255) / 256, 256, 0, stream>>>(m_b, out);
}

// Round 4
// 403.800 us; speedup vs baseline: 1.1547x; 1.1547x over previous
//
#include <hip/hip_runtime.h>
#include <hip/hip_bf16.h>
#include <stdint.h>

#define NNODES 100000
#define HID 128
#define TSZ 32
#define MDIM 16
#define ES 600000
#define ED 600000
#define ETOT (ES + ED)
#define GN (2 * NNODES)     // both branches share one node index space
#define GNP 200704          // 196 * 1024, padded for the scan
#define SCAN_BLOCKS 196
#define N16 (NNODES * MDIM) // 1,600,000

typedef unsigned short ushort_t;

__device__ __forceinline__ float bflo(unsigned u) { return __uint_as_float(u << 16); }
__device__ __forceinline__ float bfhi(unsigned u) { return __uint_as_float(u & 0xffff0000u); }

__device__ __forceinline__ float tanh_fast(float v) {
    float z = __expf(2.f * v);          // z in [0, inf]
    return 1.f - 2.f / (z + 1.f);       // z=inf -> 1, z=0 -> -1
}

// ---------------------------------------------------------------- init
// m_a[0:N16] = mask (spatial), m_a[N16:2*N16] = mask (dom); counts = 0
__global__ void k_init(const float* __restrict__ mask, float* __restrict__ m_a,
                       int* __restrict__ counts) {
    int idx = blockIdx.x * 256 + threadIdx.x;
    if (idx < N16) {
        float v = mask[idx];
        m_a[idx] = v;
        m_a[N16 + idx] = v;
    }
    if (idx < GNP) counts[idx] = 0;
}

// ---------------------------------------------------------------- PQ = [x@Wsrc + b, x@Wdst]  (bf16 out)
// LDS-tiled VALU GEMM: 64 nodes/block, 256 threads, each thread 4 nodes x 4 cols.
// Cols strided by 16 across the register tile so wl float2 reads are bank-conflict-free.
__global__ __launch_bounds__(256) void k_pq(const float* __restrict__ x,
                                            const float* __restrict__ Wt,
                                            const float* __restrict__ bt,
                                            __hip_bfloat16* __restrict__ pq) {
    __shared__ float xs[64][132];   // pad 132: float4-writable, 2-way reads (free)
    __shared__ float wl[64][130];   // pad 130: float2 reads land on 16 distinct banks
    const int tid = threadIdx.x;
    const int n0 = blockIdx.x * 64;

    // stage W transposed: wl[c][h] = c<32 ? Wt[h*32+c] : Wt[4096 + h*32 + (c-32)]
    for (int i = tid; i < 4096; i += 256) {
        int h = i >> 5, c = i & 31;
        float a = Wt[i];
        float b = Wt[4096 + i];
        wl[c][h] = a;
        wl[c + 32][h] = b;
    }
    // stage x: 64 nodes x 128 floats, coalesced float4
    const float4* xsrc = (const float4*)(x + (size_t)n0 * 128);
#pragma unroll
    for (int i = 0; i < 8; ++i) {
        int idx = tid + 256 * i;
        int node = idx >> 5;       // 32 float4 per node row
        int rem = idx & 31;
        if (n0 + node < NNODES) {
            float4 v = xsrc[idx];
            *(float4*)&xs[node][rem * 4] = v;
        }
    }
    __syncthreads();

    const int l = tid & 63;
    const int w = tid >> 6;
    const int c0 = l & 15;               // cols c0 + 16*b
    const int ng = w * 16 + (l >> 4) * 4; // nodes ng..ng+3 (within tile)
    float acc[4][4] = {};
#pragma unroll 4
    for (int h = 0; h < 128; h += 2) {
        float2 xv[4], wv[4];
#pragma unroll
        for (int m = 0; m < 4; ++m) xv[m] = *(const float2*)&xs[ng + m][h];
#pragma unroll
        for (int m = 0; m < 4; ++m) wv[m] = *(const float2*)&wl[c0 + 16 * m][h];
#pragma unroll
        for (int a = 0; a < 4; ++a)
#pragma unroll
            for (int b = 0; b < 4; ++b)
                acc[a][b] = fmaf(xv[a].y, wv[b].y, fmaf(xv[a].x, wv[b].x, acc[a][b]));
    }
    float bv[4];
#pragma unroll
    for (int b = 0; b < 4; ++b) {
        int c = c0 + 16 * b;
        bv[b] = (c < 32) ? bt[c] : 0.f;
    }
#pragma unroll
    for (int a = 0; a < 4; ++a) {
        int node = n0 + ng + a;
        if (node < NNODES) {
#pragma unroll
            for (int b = 0; b < 4; ++b)
                pq[(size_t)node * 64 + c0 + 16 * b] = __float2bfloat16(acc[a][b] + bv[b]);
        }
    }
}

// ---------------------------------------------------------------- in-degree counts
__global__ void k_count(const int* __restrict__ sdst, const int* __restrict__ ddst,
                        int* __restrict__ counts) {
    int e = blockIdx.x * 256 + threadIdx.x;
    if (e >= ETOT) return;
    int gd = (e < ES) ? sdst[e] : (ddst[e - ES] + NNODES);
    atomicAdd(&counts[gd], 1);
}

// ---------------------------------------------------------------- scan (3 kernels)
__global__ __launch_bounds__(256) void k_scan1(const int* __restrict__ counts,
                                               int* __restrict__ bsum) {
    __shared__ int sh[256];
    int tid = threadIdx.x;
    int4 v = ((const int4*)counts)[blockIdx.x * 256 + tid];
    sh[tid] = v.x + v.y + v.z + v.w;
    __syncthreads();
    for (int o = 128; o > 0; o >>= 1) {
        if (tid < o) sh[tid] += sh[tid + o];
        __syncthreads();
    }
    if (tid == 0) bsum[blockIdx.x] = sh[0];
}

__global__ __launch_bounds__(256) void k_scan2(const int* __restrict__ bsum,
                                               int* __restrict__ prefix) {
    __shared__ int sh[256];
    int tid = threadIdx.x;
    int v = (tid < SCAN_BLOCKS) ? bsum[tid] : 0;
    sh[tid] = v;
    __syncthreads();
    for (int o = 1; o < 256; o <<= 1) {
        int add = (tid >= o) ? sh[tid - o] : 0;
        __syncthreads();
        sh[tid] += add;
        __syncthreads();
    }
    prefix[tid] = sh[tid] - v; // exclusive
}

__global__ __launch_bounds__(256) void k_scan3(const int* __restrict__ counts,
                                               const int* __restrict__ prefix,
                                               int* __restrict__ off,
                                               int* __restrict__ cursor) {
    __shared__ int sh[256];
    int tid = threadIdx.x;
    int4 v = ((const int4*)counts)[blockIdx.x * 256 + tid];
    int tot = v.x + v.y + v.z + v.w;
    sh[tid] = tot;
    __syncthreads();
    for (int o = 1; o < 256; o <<= 1) {
        int add = (tid >= o) ? sh[tid - o] : 0;
        __syncthreads();
        sh[tid] += add;
        __syncthreads();
    }
    int excl = sh[tid] - tot + prefix[blockIdx.x];
    int4 o4;
    o4.x = excl;
    o4.y = o4.x + v.x;
    o4.z = o4.y + v.y;
    o4.w = o4.z + v.z;
    ((int4*)off)[blockIdx.x * 256 + tid] = o4;
    ((int4*)cursor)[blockIdx.x * 256 + tid] = o4;
}

// ---------------------------------------------------------------- ew + CSR fill
// per edge: ew = sigmoid(attr@Wa + sum_t tanh(P[src][t]+Q[dst][t]) * Wt[t] + b)
// then csr[atomicAdd(cursor[dst_g])] = {src_g, ew_bits}
__global__ void k_ewfill(const ushort_t* __restrict__ pq,
                         const int* __restrict__ ssrc, const int* __restrict__ sdst,
                         const int* __restrict__ dsrc, const int* __restrict__ ddst,
                         const float* __restrict__ sattr, const float* __restrict__ dattr,
                         const float* __restrict__ Wp, const float* __restrict__ bp,
                         const float* __restrict__ Wd, const float* __restrict__ bd,
                         int* __restrict__ cursor, int2* __restrict__ csr) {
    int e = blockIdx.x * 256 + threadIdx.x;
    if (e >= ETOT) return;
    int src, dstg, srcg;
    float acc;
    const float* wt;
    if (e < ES) {
        src = ssrc[e];
        int dst = sdst[e];
        dstg = dst;
        srcg = src;
        const float4 a = *(const float4*)(sattr + (size_t)e * 4);
        acc = bp[0] + a.x * Wp[0] + a.y * Wp[1] + a.z * Wp[2] + a.w * Wp[3];
        wt = Wp + 4;
        const uint4* Pp = (const uint4*)(pq + (size_t)src * 64);
        const uint4* Qp = (const uint4*)(pq + (size_t)dst * 64 + 32);
#pragma unroll
        for (int c = 0; c < 4; ++c) {
            uint4 pu = Pp[c], qu = Qp[c];
            unsigned pw[4] = {pu.x, pu.y, pu.z, pu.w};
            unsigned qw[4] = {qu.x, qu.y, qu.z, qu.w};
#pragma unroll
            for (int k = 0; k < 4; ++k) {
                float v0 = bflo(pw[k]) + bflo(qw[k]);
                float v1 = bfhi(pw[k]) + bfhi(qw[k]);
                int t = c * 8 + k * 2;
                acc = fmaf(tanh_fast(v0), wt[t], acc);
                acc = fmaf(tanh_fast(v1), wt[t + 1], acc);
            }
        }
    } else {
        int ed = e - ES;
        src = dsrc[ed];
        int dst = ddst[ed];
        dstg = dst + NNODES;
        srcg = src + NNODES;
        acc = bd[0] + dattr[ed] * Wd[0];
        wt = Wd + 1;
        const uint4* Pp = (const uint4*)(pq + (size_t)src * 64);
        const uint4* Qp = (const uint4*)(pq + (size_t)dst * 64 + 32);
#pragma unroll
        for (int c = 0; c < 4; ++c) {
            uint4 pu = Pp[c], qu = Qp[c];
            unsigned pw[4] = {pu.x, pu.y, pu.z, pu.w};
            unsigned qw[4] = {qu.x, qu.y, qu.z, qu.w};
#pragma unroll
            for (int k = 0; k < 4; ++k) {
                float v0 = bflo(pw[k]) + bflo(qw[k]);
                float v1 = bfhi(pw[k]) + bfhi(qw[k]);
                int t = c * 8 + k * 2;
                acc = fmaf(tanh_fast(v0), wt[t], acc);
                acc = fmaf(tanh_fast(v1), wt[t + 1], acc);
            }
        }
    }
    float ew = 1.f / (1.f + __expf(-acc));
    int pos = atomicAdd(&cursor[dstg], 1);
    csr[pos] = make_int2(srcg, __float_as_int(ew));
}

// ---------------------------------------------------------------- one propagation round (gather, no atomics)
__global__ void k_round(const float* __restrict__ m_in, float* __restrict__ m_out,
                        const int* __restrict__ off, const int2* __restrict__ csr) {
    int idx = blockIdx.x * 256 + threadIdx.x;
    if (idx >= GN * MDIM) return;
    int g = idx >> 4;
    int j = idx & 15;
    int p0 = off[g], p1 = off[g + 1];
    float vmax = m_in[idx];
    for (int p = p0; p < p1; ++p) {
        int2 en = csr[p];
        float v = m_in[(en.x << 4) + j] * __int_as_float(en.y);
        vmax = fmaxf(vmax, v);
    }
    m_out[idx] = vmax;
}

// ---------------------------------------------------------------- final round fused with branch combine
// thread = (spatial node g, dim j); also handles dom node g+NNODES, writes max of both.
__global__ void k_round_final(const float* __restrict__ m_in, float* __restrict__ out,
                              const int* __restrict__ off, const int2* __restrict__ csr) {
    int idx = blockIdx.x * 256 + threadIdx.x;
    if (idx >= N16) return;
    int g = idx >> 4;
    int j = idx & 15;
    float v1 = m_in[idx];
    {
        int p0 = off[g], p1 = off[g + 1];
        for (int p = p0; p < p1; ++p) {
            int2 en = csr[p];
            v1 = fmaxf(v1, m_in[(en.x << 4) + j] * __int_as_float(en.y));
        }
    }
    float v2 = m_in[N16 + idx];
    {
        int g2 = g + NNODES;
        int p0 = off[g2], p1 = off[g2 + 1];
        for (int p = p0; p < p1; ++p) {
            int2 en = csr[p];
            v2 = fmaxf(v2, m_in[(en.x << 4) + j] * __int_as_float(en.y));
        }
    }
    out[idx] = fmaxf(v1, v2);
}

extern "C" void kernel_launch(void* const* d_in, const int* in_sizes, int n_in,
                              void* d_out, int out_size, void* d_ws, size_t ws_size,
                              hipStream_t stream) {
    const float* x     = (const float*)d_in[0];
    const float* mask  = (const float*)d_in[1];
    const int*   sei   = (const int*)d_in[2];
    const int*   dei   = (const int*)d_in[3];
    const float* sattr = (const float*)d_in[4];
    const float* dattr = (const float*)d_in[5];
    const float* Wt    = (const float*)d_in[6];
    const float* bt    = (const float*)d_in[7];
    const float* Wp    = (const float*)d_in[8];
    const float* bp    = (const float*)d_in[9];
    const float* Wd    = (const float*)d_in[10];
    const float* bd    = (const float*)d_in[11];
    float* out = (float*)d_out;

    char* ws = (char*)d_ws;
    size_t o = 0;
    auto take = [&](size_t bytes) -> char* {
        char* p = ws + o;
        o = (o + bytes + 255) & ~(size_t)255;
        return p;
    };
    __hip_bfloat16* pq = (__hip_bfloat16*)take((size_t)NNODES * 64 * 2);
    int* counts = (int*)take((size_t)GNP * 4);
    int* off    = (int*)take((size_t)GNP * 4);
    int* cursor = (int*)take((size_t)GNP * 4);
    int* bsum   = (int*)take(256 * 4);
    int* prefix = (int*)take(256 * 4);
    int2* csr   = (int2*)take((size_t)ETOT * 8);
    float* m_a  = (float*)take((size_t)2 * N16 * 4);
    float* m_b  = (float*)take((size_t)2 * N16 * 4);

    k_init<<<6250, 256, 0, stream>>>(mask, m_a, counts);
    k_pq<<<(NNODES + 63) / 64, 256, 0, stream>>>(x, Wt, bt, pq);
    k_count<<<(ETOT + 255) / 256, 256, 0, stream>>>(sei + ES, dei + ED, counts);
    k_scan1<<<SCAN_BLOCKS, 256, 0, stream>>>(counts, bsum);
    k_scan2<<<1, 256, 0, stream>>>(bsum, prefix);
    k_scan3<<<SCAN_BLOCKS, 256, 0, stream>>>(counts, prefix, off, cursor);
    k_ewfill<<<(ETOT + 255) / 256, 256, 0, stream>>>((const ushort_t*)pq,
        sei, sei + ES, dei, dei + ED, sattr, dattr, Wp, bp, Wd, bd, cursor, csr);
    k_round<<<(GN * MDIM) / 256, 256, 0, stream>>>(m_a, m_b, off, csr);
    k_round<<<(GN * MDIM) / 256, 256, 0, stream>>>(m_b, m_a, off, csr);
    k_round_final<<<(N16 + 255) / 256, 256, 0, stream>>>(m_a, out, off, csr);
}

// Round 5
// 352.303 us; speedup vs baseline: 1.3235x; 1.1462x over previous
//
#include <hip/hip_runtime.h>
#include <hip/hip_bf16.h>
#include <stdint.h>

#define NNODES 100000
#define HID 128
#define TSZ 32
#define MDIM 16
#define ES 600000
#define ED 600000
#define ETOT (ES + ED)
#define GN (2 * NNODES)     // both branches share one node index space
#define GNP 200704          // 196 * 1024, padded for the scan
#define SCAN_BLOCKS 196
#define N16 (NNODES * MDIM) // 1,600,000
#define NP8 (NNODES * 8)    // 800,000 packed pairs per branch
#define GN8 (GN * 8)        // 1,600,000 packed pairs total

typedef unsigned short ushort_t;

__device__ __forceinline__ float bflo(unsigned u) { return __uint_as_float(u << 16); }
__device__ __forceinline__ float bfhi(unsigned u) { return __uint_as_float(u & 0xffff0000u); }

// RNE fp32 -> bf16 (finite inputs only)
__device__ __forceinline__ unsigned f2bf(float f) {
    unsigned u = __float_as_uint(f);
    return (u + 0x7FFFu + ((u >> 16) & 1u)) >> 16;
}
__device__ __forceinline__ unsigned packbf(float lo, float hi) {
    return f2bf(lo) | (f2bf(hi) << 16);
}

__device__ __forceinline__ float tanh_fast(float v) {
    float z = __expf(2.f * v);          // z in [0, inf]
    return 1.f - 2.f / (z + 1.f);       // z=inf -> 1, z=0 -> -1
}

// ---------------------------------------------------------------- init
// m_a = packed-bf16 mask for both branches; counts = 0
__global__ void k_init(const float* __restrict__ mask, unsigned* __restrict__ m_a,
                       int* __restrict__ counts) {
    int idx = blockIdx.x * 256 + threadIdx.x;   // 3125 blocks -> 800000 threads
    if (idx < NP8) {
        float2 v = ((const float2*)mask)[idx];
        unsigned p = packbf(v.x, v.y);
        m_a[idx] = p;
        m_a[NP8 + idx] = p;
    }
    if (idx < GNP / 4) ((int4*)counts)[idx] = make_int4(0, 0, 0, 0);
}

// ---------------------------------------------------------------- PQ = [x@Wsrc + b, x@Wdst]  (bf16 out)
// LDS-tiled VALU GEMM: 64 nodes/block, 256 threads, each thread 4 nodes x 4 cols.
__global__ __launch_bounds__(256) void k_pq(const float* __restrict__ x,
                                            const float* __restrict__ Wt,
                                            const float* __restrict__ bt,
                                            __hip_bfloat16* __restrict__ pq) {
    __shared__ float xs[64][132];   // pad 132: float4-writable, 2-way reads (free)
    __shared__ float wl[64][130];   // pad 130: float2 reads land on 16 distinct banks
    const int tid = threadIdx.x;
    const int n0 = blockIdx.x * 64;

    for (int i = tid; i < 4096; i += 256) {
        int h = i >> 5, c = i & 31;
        float a = Wt[i];
        float b = Wt[4096 + i];
        wl[c][h] = a;
        wl[c + 32][h] = b;
    }
    const float4* xsrc = (const float4*)(x + (size_t)n0 * 128);
#pragma unroll
    for (int i = 0; i < 8; ++i) {
        int idx = tid + 256 * i;
        int node = idx >> 5;
        int rem = idx & 31;
        if (n0 + node < NNODES) {
            float4 v = xsrc[idx];
            *(float4*)&xs[node][rem * 4] = v;
        }
    }
    __syncthreads();

    const int l = tid & 63;
    const int w = tid >> 6;
    const int c0 = l & 15;
    const int ng = w * 16 + (l >> 4) * 4;
    float acc[4][4] = {};
#pragma unroll 4
    for (int h = 0; h < 128; h += 2) {
        float2 xv[4], wv[4];
#pragma unroll
        for (int m = 0; m < 4; ++m) xv[m] = *(const float2*)&xs[ng + m][h];
#pragma unroll
        for (int m = 0; m < 4; ++m) wv[m] = *(const float2*)&wl[c0 + 16 * m][h];
#pragma unroll
        for (int a = 0; a < 4; ++a)
#pragma unroll
            for (int b = 0; b < 4; ++b)
                acc[a][b] = fmaf(xv[a].y, wv[b].y, fmaf(xv[a].x, wv[b].x, acc[a][b]));
    }
    float bv[4];
#pragma unroll
    for (int b = 0; b < 4; ++b) {
        int c = c0 + 16 * b;
        bv[b] = (c < 32) ? bt[c] : 0.f;
    }
#pragma unroll
    for (int a = 0; a < 4; ++a) {
        int node = n0 + ng + a;
        if (node < NNODES) {
#pragma unroll
            for (int b = 0; b < 4; ++b)
                pq[(size_t)node * 64 + c0 + 16 * b] = __float2bfloat16(acc[a][b] + bv[b]);
        }
    }
}

// ---------------------------------------------------------------- in-degree counts
__global__ void k_count(const int* __restrict__ sdst, const int* __restrict__ ddst,
                        int* __restrict__ counts) {
    int e = blockIdx.x * 256 + threadIdx.x;
    if (e >= ETOT) return;
    int gd = (e < ES) ? sdst[e] : (ddst[e - ES] + NNODES);
    atomicAdd(&counts[gd], 1);
}

// ---------------------------------------------------------------- scan (3 kernels)
__global__ __launch_bounds__(256) void k_scan1(const int* __restrict__ counts,
                                               int* __restrict__ bsum) {
    __shared__ int sh[256];
    int tid = threadIdx.x;
    int4 v = ((const int4*)counts)[blockIdx.x * 256 + tid];
    sh[tid] = v.x + v.y + v.z + v.w;
    __syncthreads();
    for (int o = 128; o > 0; o >>= 1) {
        if (tid < o) sh[tid] += sh[tid + o];
        __syncthreads();
    }
    if (tid == 0) bsum[blockIdx.x] = sh[0];
}

__global__ __launch_bounds__(256) void k_scan2(const int* __restrict__ bsum,
                                               int* __restrict__ prefix) {
    __shared__ int sh[256];
    int tid = threadIdx.x;
    int v = (tid < SCAN_BLOCKS) ? bsum[tid] : 0;
    sh[tid] = v;
    __syncthreads();
    for (int o = 1; o < 256; o <<= 1) {
        int add = (tid >= o) ? sh[tid - o] : 0;
        __syncthreads();
        sh[tid] += add;
        __syncthreads();
    }
    prefix[tid] = sh[tid] - v; // exclusive
}

__global__ __launch_bounds__(256) void k_scan3(const int* __restrict__ counts,
                                               const int* __restrict__ prefix,
                                               int* __restrict__ off,
                                               int* __restrict__ cursor) {
    __shared__ int sh[256];
    int tid = threadIdx.x;
    int4 v = ((const int4*)counts)[blockIdx.x * 256 + tid];
    int tot = v.x + v.y + v.z + v.w;
    sh[tid] = tot;
    __syncthreads();
    for (int o = 1; o < 256; o <<= 1) {
        int add = (tid >= o) ? sh[tid - o] : 0;
        __syncthreads();
        sh[tid] += add;
        __syncthreads();
    }
    int excl = sh[tid] - tot + prefix[blockIdx.x];
    int4 o4;
    o4.x = excl;
    o4.y = o4.x + v.x;
    o4.z = o4.y + v.y;
    o4.w = o4.z + v.z;
    ((int4*)off)[blockIdx.x * 256 + tid] = o4;
    ((int4*)cursor)[blockIdx.x * 256 + tid] = o4;
}

// ---------------------------------------------------------------- ew + CSR fill
// csr entry = (src_g << 14) | ew14  (ew in 14-bit fixed point, step 1/16383)
__global__ void k_ewfill(const ushort_t* __restrict__ pq,
                         const int* __restrict__ ssrc, const int* __restrict__ sdst,
                         const int* __restrict__ dsrc, const int* __restrict__ ddst,
                         const float* __restrict__ sattr, const float* __restrict__ dattr,
                         const float* __restrict__ Wp, const float* __restrict__ bp,
                         const float* __restrict__ Wd, const float* __restrict__ bd,
                         int* __restrict__ cursor, unsigned* __restrict__ csr) {
    int e = blockIdx.x * 256 + threadIdx.x;
    if (e >= ETOT) return;
    int src, dstg, srcg;
    float acc;
    const float* wt;
    if (e < ES) {
        src = ssrc[e];
        int dst = sdst[e];
        dstg = dst;
        srcg = src;
        const float4 a = *(const float4*)(sattr + (size_t)e * 4);
        acc = bp[0] + a.x * Wp[0] + a.y * Wp[1] + a.z * Wp[2] + a.w * Wp[3];
        wt = Wp + 4;
        const uint4* Pp = (const uint4*)(pq + (size_t)src * 64);
        const uint4* Qp = (const uint4*)(pq + (size_t)dst * 64 + 32);
#pragma unroll
        for (int c = 0; c < 4; ++c) {
            uint4 pu = Pp[c], qu = Qp[c];
            unsigned pw[4] = {pu.x, pu.y, pu.z, pu.w};
            unsigned qw[4] = {qu.x, qu.y, qu.z, qu.w};
#pragma unroll
            for (int k = 0; k < 4; ++k) {
                float v0 = bflo(pw[k]) + bflo(qw[k]);
                float v1 = bfhi(pw[k]) + bfhi(qw[k]);
                int t = c * 8 + k * 2;
                acc = fmaf(tanh_fast(v0), wt[t], acc);
                acc = fmaf(tanh_fast(v1), wt[t + 1], acc);
            }
        }
    } else {
        int ed = e - ES;
        src = dsrc[ed];
        int dst = ddst[ed];
        dstg = dst + NNODES;
        srcg = src + NNODES;
        acc = bd[0] + dattr[ed] * Wd[0];
        wt = Wd + 1;
        const uint4* Pp = (const uint4*)(pq + (size_t)src * 64);
        const uint4* Qp = (const uint4*)(pq + (size_t)dst * 64 + 32);
#pragma unroll
        for (int c = 0; c < 4; ++c) {
            uint4 pu = Pp[c], qu = Qp[c];
            unsigned pw[4] = {pu.x, pu.y, pu.z, pu.w};
            unsigned qw[4] = {qu.x, qu.y, qu.z, qu.w};
#pragma unroll
            for (int k = 0; k < 4; ++k) {
                float v0 = bflo(pw[k]) + bflo(qw[k]);
                float v1 = bfhi(pw[k]) + bfhi(qw[k]);
                int t = c * 8 + k * 2;
                acc = fmaf(tanh_fast(v0), wt[t], acc);
                acc = fmaf(tanh_fast(v1), wt[t + 1], acc);
            }
        }
    }
    float ew = 1.f / (1.f + __expf(-acc));
    unsigned entry = ((unsigned)srcg << 14) | (unsigned)(ew * 16383.f + 0.5f);
    int pos = atomicAdd(&cursor[dstg], 1);
    csr[pos] = entry;
}

// ---------------------------------------------------------------- one propagation round
// thread = (global node g, packed dim-pair jp). 2-way unrolled edge loop.
__global__ void k_round(const unsigned* __restrict__ m_in, unsigned* __restrict__ m_out,
                        const int* __restrict__ off, const unsigned* __restrict__ csr) {
    int idx = blockIdx.x * 256 + threadIdx.x;
    if (idx >= GN8) return;
    int g = idx >> 3;
    int jp = idx & 7;
    int p0 = off[g], p1 = off[g + 1];
    unsigned cur = m_in[idx];
    float a = bflo(cur), b = bfhi(cur);
    int p = p0;
    for (; p + 1 < p1; p += 2) {
        unsigned e0 = csr[p], e1 = csr[p + 1];
        unsigned m0 = m_in[(e0 >> 14) * 8 + jp];
        unsigned m1 = m_in[(e1 >> 14) * 8 + jp];
        float w0 = (float)(e0 & 16383u) * (1.f / 16383.f);
        float w1 = (float)(e1 & 16383u) * (1.f / 16383.f);
        a = fmaxf(a, fmaxf(bflo(m0) * w0, bflo(m1) * w1));
        b = fmaxf(b, fmaxf(bfhi(m0) * w0, bfhi(m1) * w1));
    }
    if (p < p1) {
        unsigned e0 = csr[p];
        unsigned m0 = m_in[(e0 >> 14) * 8 + jp];
        float w0 = (float)(e0 & 16383u) * (1.f / 16383.f);
        a = fmaxf(a, bflo(m0) * w0);
        b = fmaxf(b, bfhi(m0) * w0);
    }
    m_out[idx] = packbf(a, b);
}

// ---------------------------------------------------------------- final round fused with branch combine
__global__ void k_round_final(const unsigned* __restrict__ m_in, float* __restrict__ out,
                              const int* __restrict__ off, const unsigned* __restrict__ csr) {
    int idx = blockIdx.x * 256 + threadIdx.x;
    if (idx >= NP8) return;
    int g = idx >> 3;
    int jp = idx & 7;
    float a, b;
    {
        unsigned cur = m_in[idx];
        a = bflo(cur); b = bfhi(cur);
        int p0 = off[g], p1 = off[g + 1];
        int p = p0;
        for (; p + 1 < p1; p += 2) {
            unsigned e0 = csr[p], e1 = csr[p + 1];
            unsigned m0 = m_in[(e0 >> 14) * 8 + jp];
            unsigned m1 = m_in[(e1 >> 14) * 8 + jp];
            float w0 = (float)(e0 & 16383u) * (1.f / 16383.f);
            float w1 = (float)(e1 & 16383u) * (1.f / 16383.f);
            a = fmaxf(a, fmaxf(bflo(m0) * w0, bflo(m1) * w1));
            b = fmaxf(b, fmaxf(bfhi(m0) * w0, bfhi(m1) * w1));
        }
        if (p < p1) {
            unsigned e0 = csr[p];
            unsigned m0 = m_in[(e0 >> 14) * 8 + jp];
            float w0 = (float)(e0 & 16383u) * (1.f / 16383.f);
            a = fmaxf(a, bflo(m0) * w0);
            b = fmaxf(b, bfhi(m0) * w0);
        }
    }
    {
        unsigned cur = m_in[NP8 + idx];
        float a2 = bflo(cur), b2 = bfhi(cur);
        int g2 = g + NNODES;
        int p0 = off[g2], p1 = off[g2 + 1];
        int p = p0;
        for (; p + 1 < p1; p += 2) {
            unsigned e0 = csr[p], e1 = csr[p + 1];
            unsigned m0 = m_in[(e0 >> 14) * 8 + jp];
            unsigned m1 = m_in[(e1 >> 14) * 8 + jp];
            float w0 = (float)(e0 & 16383u) * (1.f / 16383.f);
            float w1 = (float)(e1 & 16383u) * (1.f / 16383.f);
            a2 = fmaxf(a2, fmaxf(bflo(m0) * w0, bflo(m1) * w1));
            b2 = fmaxf(b2, fmaxf(bfhi(m0) * w0, bfhi(m1) * w1));
        }
        if (p < p1) {
            unsigned e0 = csr[p];
            unsigned m0 = m_in[(e0 >> 14) * 8 + jp];
            float w0 = (float)(e0 & 16383u) * (1.f / 16383.f);
            a2 = fmaxf(a2, bflo(m0) * w0);
            b2 = fmaxf(b2, bfhi(m0) * w0);
        }
        a = fmaxf(a, a2);
        b = fmaxf(b, b2);
    }
    *(float2*)&out[g * 16 + jp * 2] = make_float2(a, b);
}

extern "C" void kernel_launch(void* const* d_in, const int* in_sizes, int n_in,
                              void* d_out, int out_size, void* d_ws, size_t ws_size,
                              hipStream_t stream) {
    const float* x     = (const float*)d_in[0];
    const float* mask  = (const float*)d_in[1];
    const int*   sei   = (const int*)d_in[2];
    const int*   dei   = (const int*)d_in[3];
    const float* sattr = (const float*)d_in[4];
    const float* dattr = (const float*)d_in[5];
    const float* Wt    = (const float*)d_in[6];
    const float* bt    = (const float*)d_in[7];
    const float* Wp    = (const float*)d_in[8];
    const float* bp    = (const float*)d_in[9];
    const float* Wd    = (const float*)d_in[10];
    const float* bd    = (const float*)d_in[11];
    float* out = (float*)d_out;

    char* ws = (char*)d_ws;
    size_t o = 0;
    auto take = [&](size_t bytes) -> char* {
        char* p = ws + o;
        o = (o + bytes + 255) & ~(size_t)255;
        return p;
    };
    __hip_bfloat16* pq = (__hip_bfloat16*)take((size_t)NNODES * 64 * 2);
    int* counts  = (int*)take((size_t)GNP * 4);
    int* off     = (int*)take((size_t)GNP * 4);
    int* cursor  = (int*)take((size_t)GNP * 4);
    int* bsum    = (int*)take(256 * 4);
    int* prefix  = (int*)take(256 * 4);
    unsigned* csr = (unsigned*)take((size_t)ETOT * 4);
    unsigned* m_a = (unsigned*)take((size_t)GN8 * 4);
    unsigned* m_b = (unsigned*)take((size_t)GN8 * 4);

    k_init<<<3125, 256, 0, stream>>>(mask, m_a, counts);
    k_pq<<<(NNODES + 63) / 64, 256, 0, stream>>>(x, Wt, bt, pq);
    k_count<<<(ETOT + 255) / 256, 256, 0, stream>>>(sei + ES, dei + ED, counts);
    k_scan1<<<SCAN_BLOCKS, 256, 0, stream>>>(counts, bsum);
    k_scan2<<<1, 256, 0, stream>>>(bsum, prefix);
    k_scan3<<<SCAN_BLOCKS, 256, 0, stream>>>(counts, prefix, off, cursor);
    k_ewfill<<<(ETOT + 255) / 256, 256, 0, stream>>>((const ushort_t*)pq,
        sei, sei + ES, dei, dei + ED, sattr, dattr, Wp, bp, Wd, bd, cursor, csr);
    k_round<<<(GN8 + 255) / 256, 256, 0, stream>>>(m_a, m_b, off, csr);
    k_round<<<(GN8 + 255) / 256, 256, 0, stream>>>(m_b, m_a, off, csr);
    k_round_final<<<(NP8 + 255) / 256, 256, 0, stream>>>(m_a, out, off, csr);
}

// Round 6
// 342.156 us; speedup vs baseline: 1.3628x; 1.0297x over previous
//
#include <hip/hip_runtime.h>
#include <hip/hip_bf16.h>
#include <stdint.h>

#define NNODES 100000
#define HID 128
#define TSZ 32
#define MDIM 16
#define ES 600000
#define ED 600000
#define ETOT (ES + ED)
#define GN (2 * NNODES)     // both branches share one node index space
#define GNP 200704          // 196 * 1024, padded for the scan
#define SCAN_BLOCKS 196
#define N16 (NNODES * MDIM) // 1,600,000
#define NP8 (NNODES * 8)    // 800,000 packed pairs per branch
#define GN8 (GN * 8)        // 1,600,000 packed pairs total
#define PQ_BLOCKS 1563      // ceil(NNODES/64)

typedef unsigned short ushort_t;

__device__ __forceinline__ float bflo(unsigned u) { return __uint_as_float(u << 16); }
__device__ __forceinline__ float bfhi(unsigned u) { return __uint_as_float(u & 0xffff0000u); }

// RNE fp32 -> bf16 (finite inputs only)
__device__ __forceinline__ unsigned f2bf(float f) {
    unsigned u = __float_as_uint(f);
    return (u + 0x7FFFu + ((u >> 16) & 1u)) >> 16;
}
__device__ __forceinline__ unsigned packbf(float lo, float hi) {
    return f2bf(lo) | (f2bf(hi) << 16);
}

__device__ __forceinline__ float tanh_fast(float v) {
    float z = __expf(2.f * v);          // z in [0, inf]
    return 1.f - 2.f / (z + 1.f);       // z=inf -> 1, z=0 -> -1
}

// ---------------------------------------------------------------- init
// m_a = packed-bf16 mask for both branches; counts = 0
__global__ void k_init(const float* __restrict__ mask, unsigned* __restrict__ m_a,
                       int* __restrict__ counts) {
    int idx = blockIdx.x * 256 + threadIdx.x;   // 3125 blocks -> 800000 threads
    if (idx < NP8) {
        float2 v = ((const float2*)mask)[idx];
        unsigned p = packbf(v.x, v.y);
        m_a[idx] = p;
        m_a[NP8 + idx] = p;
    }
    if (idx < GNP / 4) ((int4*)counts)[idx] = make_int4(0, 0, 0, 0);
}

// ---------------------------------------------------------------- PQ = [x@Wsrc + b, x@Wdst]  (int8 out, step 1/32, clamp +-127)
// LDS-tiled VALU GEMM: 64 nodes/block, 256 threads, each thread 4 nodes x 4 cols.
// Epilogue repacks int8 through LDS for coalesced dword4 stores.
__global__ __launch_bounds__(256) void k_pq(const float* __restrict__ x,
                                            const float* __restrict__ Wt,
                                            const float* __restrict__ bt,
                                            char* __restrict__ pq) {
    __shared__ float xs[64][132];   // pad 132: float4-writable, 2-way reads (free)
    __shared__ float wl[64][130];   // pad 130: float2 reads land on 16 distinct banks
    const int tid = threadIdx.x;
    const int n0 = blockIdx.x * 64;

    for (int i = tid; i < 4096; i += 256) {
        int h = i >> 5, c = i & 31;
        float a = Wt[i];
        float b = Wt[4096 + i];
        wl[c][h] = a;
        wl[c + 32][h] = b;
    }
    const float4* xsrc = (const float4*)(x + (size_t)n0 * 128);
#pragma unroll
    for (int i = 0; i < 8; ++i) {
        int idx = tid + 256 * i;
        int node = idx >> 5;
        int rem = idx & 31;
        if (n0 + node < NNODES) {
            float4 v = xsrc[idx];
            *(float4*)&xs[node][rem * 4] = v;
        }
    }
    __syncthreads();

    const int l = tid & 63;
    const int w = tid >> 6;
    const int c0 = l & 15;
    const int ng = w * 16 + (l >> 4) * 4;
    float acc[4][4] = {};
#pragma unroll 4
    for (int h = 0; h < 128; h += 2) {
        float2 xv[4], wv[4];
#pragma unroll
        for (int m = 0; m < 4; ++m) xv[m] = *(const float2*)&xs[ng + m][h];
#pragma unroll
        for (int m = 0; m < 4; ++m) wv[m] = *(const float2*)&wl[c0 + 16 * m][h];
#pragma unroll
        for (int a = 0; a < 4; ++a)
#pragma unroll
            for (int b = 0; b < 4; ++b)
                acc[a][b] = fmaf(xv[a].y, wv[b].y, fmaf(xv[a].x, wv[b].x, acc[a][b]));
    }
    float bv[4];
#pragma unroll
    for (int b = 0; b < 4; ++b) {
        int c = c0 + 16 * b;
        bv[b] = (c < 32) ? bt[c] : 0.f;
    }
    __syncthreads();                 // all xs/wl reads done; reuse xs as byte buffer
    char* buf = (char*)&xs[0][0];    // flat [64 nodes][64 bytes]
#pragma unroll
    for (int a = 0; a < 4; ++a) {
#pragma unroll
        for (int b = 0; b < 4; ++b) {
            float v = acc[a][b] + bv[b];
            int q = __float2int_rn(v * 32.f);
            q = max(-127, min(127, q));
            buf[(ng + a) * 64 + c0 + 16 * b] = (char)q;
        }
    }
    __syncthreads();
    uint4 v4 = ((const uint4*)buf)[tid];
    ((uint4*)(pq + (size_t)blockIdx.x * 4096))[tid] = v4;
}

// ---------------------------------------------------------------- in-degree counts
__global__ void k_count(const int* __restrict__ sdst, const int* __restrict__ ddst,
                        int* __restrict__ counts) {
    int e = blockIdx.x * 256 + threadIdx.x;
    if (e >= ETOT) return;
    int gd = (e < ES) ? sdst[e] : (ddst[e - ES] + NNODES);
    atomicAdd(&counts[gd], 1);
}

// ---------------------------------------------------------------- scan (3 kernels)
__global__ __launch_bounds__(256) void k_scan1(const int* __restrict__ counts,
                                               int* __restrict__ bsum) {
    __shared__ int sh[256];
    int tid = threadIdx.x;
    int4 v = ((const int4*)counts)[blockIdx.x * 256 + tid];
    sh[tid] = v.x + v.y + v.z + v.w;
    __syncthreads();
    for (int o = 128; o > 0; o >>= 1) {
        if (tid < o) sh[tid] += sh[tid + o];
        __syncthreads();
    }
    if (tid == 0) bsum[blockIdx.x] = sh[0];
}

__global__ __launch_bounds__(256) void k_scan2(const int* __restrict__ bsum,
                                               int* __restrict__ prefix) {
    __shared__ int sh[256];
    int tid = threadIdx.x;
    int v = (tid < SCAN_BLOCKS) ? bsum[tid] : 0;
    sh[tid] = v;
    __syncthreads();
    for (int o = 1; o < 256; o <<= 1) {
        int add = (tid >= o) ? sh[tid - o] : 0;
        __syncthreads();
        sh[tid] += add;
        __syncthreads();
    }
    prefix[tid] = sh[tid] - v; // exclusive
}

__global__ __launch_bounds__(256) void k_scan3(const int* __restrict__ counts,
                                               const int* __restrict__ prefix,
                                               int* __restrict__ off,
                                               int* __restrict__ cursor) {
    __shared__ int sh[256];
    int tid = threadIdx.x;
    int4 v = ((const int4*)counts)[blockIdx.x * 256 + tid];
    int tot = v.x + v.y + v.z + v.w;
    sh[tid] = tot;
    __syncthreads();
    for (int o = 1; o < 256; o <<= 1) {
        int add = (tid >= o) ? sh[tid - o] : 0;
        __syncthreads();
        sh[tid] += add;
        __syncthreads();
    }
    int excl = sh[tid] - tot + prefix[blockIdx.x];
    int4 o4;
    o4.x = excl;
    o4.y = o4.x + v.x;
    o4.z = o4.y + v.y;
    o4.w = o4.z + v.z;
    ((int4*)off)[blockIdx.x * 256 + tid] = o4;
    ((int4*)cursor)[blockIdx.x * 256 + tid] = o4;
}

// ---------------------------------------------------------------- ew + CSR fill
// csr entry = (src_g << 14) | ew14.  P,Q are int8 (step 1/32).
__global__ void k_ewfill(const char* __restrict__ pq,
                         const int* __restrict__ ssrc, const int* __restrict__ sdst,
                         const int* __restrict__ dsrc, const int* __restrict__ ddst,
                         const float* __restrict__ sattr, const float* __restrict__ dattr,
                         const float* __restrict__ Wp, const float* __restrict__ bp,
                         const float* __restrict__ Wd, const float* __restrict__ bd,
                         int* __restrict__ cursor, unsigned* __restrict__ csr) {
    int e = blockIdx.x * 256 + threadIdx.x;
    if (e >= ETOT) return;
    int src, dst, dstg, srcg;
    float acc;
    const float* wt;
    if (e < ES) {
        src = ssrc[e];
        dst = sdst[e];
        dstg = dst;
        srcg = src;
        const float4 a = *(const float4*)(sattr + (size_t)e * 4);
        acc = bp[0] + a.x * Wp[0] + a.y * Wp[1] + a.z * Wp[2] + a.w * Wp[3];
        wt = Wp + 4;
    } else {
        int ed = e - ES;
        src = dsrc[ed];
        dst = ddst[ed];
        dstg = dst + NNODES;
        srcg = src + NNODES;
        acc = bd[0] + dattr[ed] * Wd[0];
        wt = Wd + 1;
    }
    const uint4* Pp = (const uint4*)(pq + (size_t)src * 64);
    const uint4* Qp = (const uint4*)(pq + (size_t)dst * 64 + 32);
    uint4 pa = Pp[0], pb = Pp[1];
    uint4 qa = Qp[0], qb = Qp[1];
    unsigned pw[8] = {pa.x, pa.y, pa.z, pa.w, pb.x, pb.y, pb.z, pb.w};
    unsigned qw[8] = {qa.x, qa.y, qa.z, qa.w, qb.x, qb.y, qb.z, qb.w};
#pragma unroll
    for (int d = 0; d < 8; ++d) {
        unsigned a = pw[d], b = qw[d];
#pragma unroll
        for (int k = 0; k < 4; ++k) {
            int pi = (int)(char)(a >> (8 * k));
            int qi = (int)(char)(b >> (8 * k));
            float t = tanh_fast((float)(pi + qi) * 0.03125f);
            acc = fmaf(t, wt[d * 4 + k], acc);
        }
    }
    float ew = 1.f / (1.f + __expf(-acc));
    unsigned entry = ((unsigned)srcg << 14) | (unsigned)(ew * 16383.f + 0.5f);
    int pos = atomicAdd(&cursor[dstg], 1);
    csr[pos] = entry;
}

// ---------------------------------------------------------------- one propagation round (per branch, L2-resident gather set)
// thread = (branch node g, packed dim-pair jp). 2-way unrolled edge loop.
__global__ void k_round(const unsigned* __restrict__ m_in, unsigned* __restrict__ m_out,
                        const int* __restrict__ off, const unsigned* __restrict__ csr,
                        int base) {
    int idx = blockIdx.x * 256 + threadIdx.x;
    if (idx >= NP8) return;
    int g = base + (idx >> 3);
    int jp = idx & 7;
    int mi = base * 8 + idx;
    int p0 = off[g], p1 = off[g + 1];
    unsigned cur = m_in[mi];
    float a = bflo(cur), b = bfhi(cur);
    int p = p0;
    for (; p + 1 < p1; p += 2) {
        unsigned e0 = csr[p], e1 = csr[p + 1];
        unsigned m0 = m_in[(e0 >> 14) * 8 + jp];
        unsigned m1 = m_in[(e1 >> 14) * 8 + jp];
        float w0 = (float)(e0 & 16383u) * (1.f / 16383.f);
        float w1 = (float)(e1 & 16383u) * (1.f / 16383.f);
        a = fmaxf(a, fmaxf(bflo(m0) * w0, bflo(m1) * w1));
        b = fmaxf(b, fmaxf(bfhi(m0) * w0, bfhi(m1) * w1));
    }
    if (p < p1) {
        unsigned e0 = csr[p];
        unsigned m0 = m_in[(e0 >> 14) * 8 + jp];
        float w0 = (float)(e0 & 16383u) * (1.f / 16383.f);
        a = fmaxf(a, bflo(m0) * w0);
        b = fmaxf(b, bfhi(m0) * w0);
    }
    m_out[mi] = packbf(a, b);
}

// ---------------------------------------------------------------- final round fused with branch combine
__global__ void k_round_final(const unsigned* __restrict__ m_in, float* __restrict__ out,
                              const int* __restrict__ off, const unsigned* __restrict__ csr) {
    int idx = blockIdx.x * 256 + threadIdx.x;
    if (idx >= NP8) return;
    int g = idx >> 3;
    int jp = idx & 7;
    float a, b;
    {
        unsigned cur = m_in[idx];
        a = bflo(cur); b = bfhi(cur);
        int p0 = off[g], p1 = off[g + 1];
        int p = p0;
        for (; p + 1 < p1; p += 2) {
            unsigned e0 = csr[p], e1 = csr[p + 1];
            unsigned m0 = m_in[(e0 >> 14) * 8 + jp];
            unsigned m1 = m_in[(e1 >> 14) * 8 + jp];
            float w0 = (float)(e0 & 16383u) * (1.f / 16383.f);
            float w1 = (float)(e1 & 16383u) * (1.f / 16383.f);
            a = fmaxf(a, fmaxf(bflo(m0) * w0, bflo(m1) * w1));
            b = fmaxf(b, fmaxf(bfhi(m0) * w0, bfhi(m1) * w1));
        }
        if (p < p1) {
            unsigned e0 = csr[p];
            unsigned m0 = m_in[(e0 >> 14) * 8 + jp];
            float w0 = (float)(e0 & 16383u) * (1.f / 16383.f);
            a = fmaxf(a, bflo(m0) * w0);
            b = fmaxf(b, bfhi(m0) * w0);
        }
    }
    {
        unsigned cur = m_in[NP8 + idx];
        float a2 = bflo(cur), b2 = bfhi(cur);
        int g2 = g + NNODES;
        int p0 = off[g2], p1 = off[g2 + 1];
        int p = p0;
        for (; p + 1 < p1; p += 2) {
            unsigned e0 = csr[p], e1 = csr[p + 1];
            unsigned m0 = m_in[(e0 >> 14) * 8 + jp];
            unsigned m1 = m_in[(e1 >> 14) * 8 + jp];
            float w0 = (float)(e0 & 16383u) * (1.f / 16383.f);
            float w1 = (float)(e1 & 16383u) * (1.f / 16383.f);
            a2 = fmaxf(a2, fmaxf(bflo(m0) * w0, bflo(m1) * w1));
            b2 = fmaxf(b2, fmaxf(bfhi(m0) * w0, bfhi(m1) * w1));
        }
        if (p < p1) {
            unsigned e0 = csr[p];
            unsigned m0 = m_in[(e0 >> 14) * 8 + jp];
            float w0 = (float)(e0 & 16383u) * (1.f / 16383.f);
            a2 = fmaxf(a2, bflo(m0) * w0);
            b2 = fmaxf(b2, bfhi(m0) * w0);
        }
        a = fmaxf(a, a2);
        b = fmaxf(b, b2);
    }
    *(float2*)&out[g * 16 + jp * 2] = make_float2(a, b);
}

extern "C" void kernel_launch(void* const* d_in, const int* in_sizes, int n_in,
                              void* d_out, int out_size, void* d_ws, size_t ws_size,
                              hipStream_t stream) {
    const float* x     = (const float*)d_in[0];
    const float* mask  = (const float*)d_in[1];
    const int*   sei   = (const int*)d_in[2];
    const int*   dei   = (const int*)d_in[3];
    const float* sattr = (const float*)d_in[4];
    const float* dattr = (const float*)d_in[5];
    const float* Wt    = (const float*)d_in[6];
    const float* bt    = (const float*)d_in[7];
    const float* Wp    = (const float*)d_in[8];
    const float* bp    = (const float*)d_in[9];
    const float* Wd    = (const float*)d_in[10];
    const float* bd    = (const float*)d_in[11];
    float* out = (float*)d_out;

    char* ws = (char*)d_ws;
    size_t o = 0;
    auto take = [&](size_t bytes) -> char* {
        char* p = ws + o;
        o = (o + bytes + 255) & ~(size_t)255;
        return p;
    };
    char* pq     = take((size_t)PQ_BLOCKS * 4096);
    int* counts  = (int*)take((size_t)GNP * 4);
    int* off     = (int*)take((size_t)GNP * 4);
    int* cursor  = (int*)take((size_t)GNP * 4);
    int* bsum    = (int*)take(256 * 4);
    int* prefix  = (int*)take(256 * 4);
    unsigned* csr = (unsigned*)take((size_t)ETOT * 4);
    unsigned* m_a = (unsigned*)take((size_t)GN8 * 4);
    unsigned* m_b = (unsigned*)take((size_t)GN8 * 4);

    k_init<<<3125, 256, 0, stream>>>(mask, m_a, counts);
    k_pq<<<PQ_BLOCKS, 256, 0, stream>>>(x, Wt, bt, pq);
    k_count<<<(ETOT + 255) / 256, 256, 0, stream>>>(sei + ES, dei + ED, counts);
    k_scan1<<<SCAN_BLOCKS, 256, 0, stream>>>(counts, bsum);
    k_scan2<<<1, 256, 0, stream>>>(bsum, prefix);
    k_scan3<<<SCAN_BLOCKS, 256, 0, stream>>>(counts, prefix, off, cursor);
    k_ewfill<<<(ETOT + 255) / 256, 256, 0, stream>>>(pq,
        sei, sei + ES, dei, dei + ED, sattr, dattr, Wp, bp, Wd, bd, cursor, csr);
    k_round<<<3125, 256, 0, stream>>>(m_a, m_b, off, csr, 0);
    k_round<<<3125, 256, 0, stream>>>(m_a, m_b, off, csr, NNODES);
    k_round<<<3125, 256, 0, stream>>>(m_b, m_a, off, csr, 0);
    k_round<<<3125, 256, 0, stream>>>(m_b, m_a, off, csr, NNODES);
    k_round_final<<<3125, 256, 0, stream>>>(m_a, out, off, csr);
}

// Round 7
// 332.535 us; speedup vs baseline: 1.4022x; 1.0289x over previous
//
#include <hip/hip_runtime.h>
#include <hip/hip_bf16.h>
#include <stdint.h>

#define NNODES 100000
#define HID 128
#define TSZ 32
#define MDIM 16
#define ES 600000
#define ED 600000
#define ETOT (ES + ED)
#define GN (2 * NNODES)     // both branches share one node index space
#define GNP 200704          // 196 * 1024, padded for the scan
#define SCAN_BLOCKS 196
#define N16 (NNODES * MDIM) // 1,600,000
#define NP8 (NNODES * 8)    // 800,000 packed pairs per branch
#define GN8 (GN * 8)        // 1,600,000 packed pairs total
#define PQ_BLOCKS 1563      // ceil(NNODES/64)
#define N4 (NNODES * 4)     // 400,000 round threads per branch

typedef unsigned short ushort_t;

__device__ __forceinline__ float bflo(unsigned u) { return __uint_as_float(u << 16); }
__device__ __forceinline__ float bfhi(unsigned u) { return __uint_as_float(u & 0xffff0000u); }

// RNE fp32 -> bf16 (finite inputs only)
__device__ __forceinline__ unsigned f2bf(float f) {
    unsigned u = __float_as_uint(f);
    return (u + 0x7FFFu + ((u >> 16) & 1u)) >> 16;
}
__device__ __forceinline__ unsigned packbf(float lo, float hi) {
    return f2bf(lo) | (f2bf(hi) << 16);
}

__device__ __forceinline__ float tanh_fast(float v) {
    float z = __expf(2.f * v);          // z in [0, inf]
    return 1.f - 2.f / (z + 1.f);       // z=inf -> 1, z=0 -> -1
}

// ---------------------------------------------------------------- init
__global__ void k_init(const float* __restrict__ mask, unsigned* __restrict__ m_a,
                       int* __restrict__ counts) {
    int idx = blockIdx.x * 256 + threadIdx.x;   // 3125 blocks -> 800000 threads
    if (idx < NP8) {
        float2 v = ((const float2*)mask)[idx];
        unsigned p = packbf(v.x, v.y);
        m_a[idx] = p;
        m_a[NP8 + idx] = p;
    }
    if (idx < GNP / 4) ((int4*)counts)[idx] = make_int4(0, 0, 0, 0);
}

// ---------------------------------------------------------------- PQ (int8, step 1/32)
__global__ __launch_bounds__(256) void k_pq(const float* __restrict__ x,
                                            const float* __restrict__ Wt,
                                            const float* __restrict__ bt,
                                            char* __restrict__ pq) {
    __shared__ float xs[64][132];
    __shared__ float wl[64][130];
    const int tid = threadIdx.x;
    const int n0 = blockIdx.x * 64;

    for (int i = tid; i < 4096; i += 256) {
        int h = i >> 5, c = i & 31;
        float a = Wt[i];
        float b = Wt[4096 + i];
        wl[c][h] = a;
        wl[c + 32][h] = b;
    }
    const float4* xsrc = (const float4*)(x + (size_t)n0 * 128);
#pragma unroll
    for (int i = 0; i < 8; ++i) {
        int idx = tid + 256 * i;
        int node = idx >> 5;
        int rem = idx & 31;
        if (n0 + node < NNODES) {
            float4 v = xsrc[idx];
            *(float4*)&xs[node][rem * 4] = v;
        }
    }
    __syncthreads();

    const int l = tid & 63;
    const int w = tid >> 6;
    const int c0 = l & 15;
    const int ng = w * 16 + (l >> 4) * 4;
    float acc[4][4] = {};
#pragma unroll 4
    for (int h = 0; h < 128; h += 2) {
        float2 xv[4], wv[4];
#pragma unroll
        for (int m = 0; m < 4; ++m) xv[m] = *(const float2*)&xs[ng + m][h];
#pragma unroll
        for (int m = 0; m < 4; ++m) wv[m] = *(const float2*)&wl[c0 + 16 * m][h];
#pragma unroll
        for (int a = 0; a < 4; ++a)
#pragma unroll
            for (int b = 0; b < 4; ++b)
                acc[a][b] = fmaf(xv[a].y, wv[b].y, fmaf(xv[a].x, wv[b].x, acc[a][b]));
    }
    float bv[4];
#pragma unroll
    for (int b = 0; b < 4; ++b) {
        int c = c0 + 16 * b;
        bv[b] = (c < 32) ? bt[c] : 0.f;
    }
    __syncthreads();
    char* buf = (char*)&xs[0][0];
#pragma unroll
    for (int a = 0; a < 4; ++a) {
#pragma unroll
        for (int b = 0; b < 4; ++b) {
            float v = acc[a][b] + bv[b];
            int q = __float2int_rn(v * 32.f);
            q = max(-127, min(127, q));
            buf[(ng + a) * 64 + c0 + 16 * b] = (char)q;
        }
    }
    __syncthreads();
    uint4 v4 = ((const uint4*)buf)[tid];
    ((uint4*)(pq + (size_t)blockIdx.x * 4096))[tid] = v4;
}

// ---------------------------------------------------------------- in-degree counts
__global__ void k_count(const int* __restrict__ sdst, const int* __restrict__ ddst,
                        int* __restrict__ counts) {
    int e = blockIdx.x * 256 + threadIdx.x;
    if (e >= ETOT) return;
    int gd = (e < ES) ? sdst[e] : (ddst[e - ES] + NNODES);
    atomicAdd(&counts[gd], 1);
}

// ---------------------------------------------------------------- scan (3 kernels)
__global__ __launch_bounds__(256) void k_scan1(const int* __restrict__ counts,
                                               int* __restrict__ bsum) {
    __shared__ int sh[256];
    int tid = threadIdx.x;
    int4 v = ((const int4*)counts)[blockIdx.x * 256 + tid];
    sh[tid] = v.x + v.y + v.z + v.w;
    __syncthreads();
    for (int o = 128; o > 0; o >>= 1) {
        if (tid < o) sh[tid] += sh[tid + o];
        __syncthreads();
    }
    if (tid == 0) bsum[blockIdx.x] = sh[0];
}

__global__ __launch_bounds__(256) void k_scan2(const int* __restrict__ bsum,
                                               int* __restrict__ prefix) {
    __shared__ int sh[256];
    int tid = threadIdx.x;
    int v = (tid < SCAN_BLOCKS) ? bsum[tid] : 0;
    sh[tid] = v;
    __syncthreads();
    for (int o = 1; o < 256; o <<= 1) {
        int add = (tid >= o) ? sh[tid - o] : 0;
        __syncthreads();
        sh[tid] += add;
        __syncthreads();
    }
    prefix[tid] = sh[tid] - v; // exclusive
}

__global__ __launch_bounds__(256) void k_scan3(const int* __restrict__ counts,
                                               const int* __restrict__ prefix,
                                               int* __restrict__ off,
                                               int* __restrict__ cursor) {
    __shared__ int sh[256];
    int tid = threadIdx.x;
    int4 v = ((const int4*)counts)[blockIdx.x * 256 + tid];
    int tot = v.x + v.y + v.z + v.w;
    sh[tid] = tot;
    __syncthreads();
    for (int o = 1; o < 256; o <<= 1) {
        int add = (tid >= o) ? sh[tid - o] : 0;
        __syncthreads();
        sh[tid] += add;
        __syncthreads();
    }
    int excl = sh[tid] - tot + prefix[blockIdx.x];
    int4 o4;
    o4.x = excl;
    o4.y = o4.x + v.x;
    o4.z = o4.y + v.y;
    o4.w = o4.z + v.z;
    ((int4*)off)[blockIdx.x * 256 + tid] = o4;
    ((int4*)cursor)[blockIdx.x * 256 + tid] = o4;
}

// ---------------------------------------------------------------- ew + CSR fill
__global__ void k_ewfill(const char* __restrict__ pq,
                         const int* __restrict__ ssrc, const int* __restrict__ sdst,
                         const int* __restrict__ dsrc, const int* __restrict__ ddst,
                         const float* __restrict__ sattr, const float* __restrict__ dattr,
                         const float* __restrict__ Wp, const float* __restrict__ bp,
                         const float* __restrict__ Wd, const float* __restrict__ bd,
                         int* __restrict__ cursor, unsigned* __restrict__ csr) {
    int e = blockIdx.x * 256 + threadIdx.x;
    if (e >= ETOT) return;
    int src, dst, dstg, srcg;
    float acc;
    const float* wt;
    if (e < ES) {
        src = ssrc[e];
        dst = sdst[e];
        dstg = dst;
        srcg = src;
        const float4 a = *(const float4*)(sattr + (size_t)e * 4);
        acc = bp[0] + a.x * Wp[0] + a.y * Wp[1] + a.z * Wp[2] + a.w * Wp[3];
        wt = Wp + 4;
    } else {
        int ed = e - ES;
        src = dsrc[ed];
        dst = ddst[ed];
        dstg = dst + NNODES;
        srcg = src + NNODES;
        acc = bd[0] + dattr[ed] * Wd[0];
        wt = Wd + 1;
    }
    const uint4* Pp = (const uint4*)(pq + (size_t)src * 64);
    const uint4* Qp = (const uint4*)(pq + (size_t)dst * 64 + 32);
    uint4 pa = Pp[0], pb = Pp[1];
    uint4 qa = Qp[0], qb = Qp[1];
    unsigned pw[8] = {pa.x, pa.y, pa.z, pa.w, pb.x, pb.y, pb.z, pb.w};
    unsigned qw[8] = {qa.x, qa.y, qa.z, qa.w, qb.x, qb.y, qb.z, qb.w};
#pragma unroll
    for (int d = 0; d < 8; ++d) {
        unsigned a = pw[d], b = qw[d];
#pragma unroll
        for (int k = 0; k < 4; ++k) {
            int pi = (int)(char)(a >> (8 * k));
            int qi = (int)(char)(b >> (8 * k));
            float t = tanh_fast((float)(pi + qi) * 0.03125f);
            acc = fmaf(t, wt[d * 4 + k], acc);
        }
    }
    float ew = 1.f / (1.f + __expf(-acc));
    unsigned entry = ((unsigned)srcg << 14) | (unsigned)(ew * 16383.f + 0.5f);
    int pos = atomicAdd(&cursor[dstg], 1);
    csr[pos] = entry;
}

// ---------------------------------------------------------------- propagation round
// 4 threads per node, each handles dim-pairs jp and jp+4 (two independent chains).
// Template tags give each launch a distinct name in rocprof.
template <int BASE, int TAG>
__global__ __launch_bounds__(256) void k_round_t(const unsigned* __restrict__ m_in,
                                                 unsigned* __restrict__ m_out,
                                                 const int* __restrict__ off,
                                                 const unsigned* __restrict__ csr) {
    int idx = blockIdx.x * 256 + threadIdx.x;
    if (idx >= N4) return;
    int g = BASE + (idx >> 2);
    int jp = idx & 3;
    int mi = g * 8 + jp;
    int p0 = off[g], p1 = off[g + 1];
    unsigned c0 = m_in[mi], c1 = m_in[mi + 4];
    float a0 = bflo(c0), b0 = bfhi(c0);
    float a1 = bflo(c1), b1 = bfhi(c1);
    int p = p0;
    for (; p + 1 < p1; p += 2) {
        unsigned e0 = csr[p], e1 = csr[p + 1];
        unsigned s0 = (e0 >> 14) * 8 + jp, s1 = (e1 >> 14) * 8 + jp;
        unsigned m00 = m_in[s0], m01 = m_in[s0 + 4];
        unsigned m10 = m_in[s1], m11 = m_in[s1 + 4];
        float w0 = (float)(e0 & 16383u) * (1.f / 16383.f);
        float w1 = (float)(e1 & 16383u) * (1.f / 16383.f);
        a0 = fmaxf(a0, fmaxf(bflo(m00) * w0, bflo(m10) * w1));
        b0 = fmaxf(b0, fmaxf(bfhi(m00) * w0, bfhi(m10) * w1));
        a1 = fmaxf(a1, fmaxf(bflo(m01) * w0, bflo(m11) * w1));
        b1 = fmaxf(b1, fmaxf(bfhi(m01) * w0, bfhi(m11) * w1));
    }
    if (p < p1) {
        unsigned e0 = csr[p];
        unsigned s0 = (e0 >> 14) * 8 + jp;
        unsigned m00 = m_in[s0], m01 = m_in[s0 + 4];
        float w0 = (float)(e0 & 16383u) * (1.f / 16383.f);
        a0 = fmaxf(a0, bflo(m00) * w0);
        b0 = fmaxf(b0, bfhi(m00) * w0);
        a1 = fmaxf(a1, bflo(m01) * w0);
        b1 = fmaxf(b1, bfhi(m01) * w0);
    }
    m_out[mi] = packbf(a0, b0);
    m_out[mi + 4] = packbf(a1, b1);
}

// ---------------------------------------------------------------- final round fused with branch combine
__global__ __launch_bounds__(256) void k_round_final(const unsigned* __restrict__ m_in,
                                                     float* __restrict__ out,
                                                     const int* __restrict__ off,
                                                     const unsigned* __restrict__ csr) {
    int idx = blockIdx.x * 256 + threadIdx.x;
    if (idx >= N4) return;
    int g = idx >> 2;
    int jp = idx & 3;
    float a0, b0, a1, b1;
    {
        int mi = g * 8 + jp;
        unsigned c0 = m_in[mi], c1 = m_in[mi + 4];
        a0 = bflo(c0); b0 = bfhi(c0);
        a1 = bflo(c1); b1 = bfhi(c1);
    }
    // spatial branch in-edges
    {
        int p0 = off[g], p1 = off[g + 1];
        for (int p = p0; p < p1; ++p) {
            unsigned e0 = csr[p];
            unsigned s0 = (e0 >> 14) * 8 + jp;
            unsigned m00 = m_in[s0], m01 = m_in[s0 + 4];
            float w0 = (float)(e0 & 16383u) * (1.f / 16383.f);
            a0 = fmaxf(a0, bflo(m00) * w0);
            b0 = fmaxf(b0, bfhi(m00) * w0);
            a1 = fmaxf(a1, bflo(m01) * w0);
            b1 = fmaxf(b1, bfhi(m01) * w0);
        }
    }
    // dom branch current + in-edges
    {
        int mi2 = (g + NNODES) * 8 + jp;
        unsigned c0 = m_in[mi2], c1 = m_in[mi2 + 4];
        a0 = fmaxf(a0, bflo(c0)); b0 = fmaxf(b0, bfhi(c0));
        a1 = fmaxf(a1, bflo(c1)); b1 = fmaxf(b1, bfhi(c1));
        int g2 = g + NNODES;
        int p0 = off[g2], p1 = off[g2 + 1];
        for (int p = p0; p < p1; ++p) {
            unsigned e0 = csr[p];
            unsigned s0 = (e0 >> 14) * 8 + jp;
            unsigned m00 = m_in[s0], m01 = m_in[s0 + 4];
            float w0 = (float)(e0 & 16383u) * (1.f / 16383.f);
            a0 = fmaxf(a0, bflo(m00) * w0);
            b0 = fmaxf(b0, bfhi(m00) * w0);
            a1 = fmaxf(a1, bflo(m01) * w0);
            b1 = fmaxf(b1, bfhi(m01) * w0);
        }
    }
    *(float2*)&out[g * 16 + jp * 2] = make_float2(a0, b0);
    *(float2*)&out[g * 16 + jp * 2 + 8] = make_float2(a1, b1);
}

extern "C" void kernel_launch(void* const* d_in, const int* in_sizes, int n_in,
                              void* d_out, int out_size, void* d_ws, size_t ws_size,
                              hipStream_t stream) {
    const float* x     = (const float*)d_in[0];
    const float* mask  = (const float*)d_in[1];
    const int*   sei   = (const int*)d_in[2];
    const int*   dei   = (const int*)d_in[3];
    const float* sattr = (const float*)d_in[4];
    const float* dattr = (const float*)d_in[5];
    const float* Wt    = (const float*)d_in[6];
    const float* bt    = (const float*)d_in[7];
    const float* Wp    = (const float*)d_in[8];
    const float* bp    = (const float*)d_in[9];
    const float* Wd    = (const float*)d_in[10];
    const float* bd    = (const float*)d_in[11];
    float* out = (float*)d_out;

    char* ws = (char*)d_ws;
    size_t o = 0;
    auto take = [&](size_t bytes) -> char* {
        char* p = ws + o;
        o = (o + bytes + 255) & ~(size_t)255;
        return p;
    };
    char* pq     = take((size_t)PQ_BLOCKS * 4096);
    int* counts  = (int*)take((size_t)GNP * 4);
    int* off     = (int*)take((size_t)GNP * 4);
    int* cursor  = (int*)take((size_t)GNP * 4);
    int* bsum    = (int*)take(256 * 4);
    int* prefix  = (int*)take(256 * 4);
    unsigned* csr = (unsigned*)take((size_t)ETOT * 4);
    unsigned* m_a = (unsigned*)take((size_t)GN8 * 4);
    unsigned* m_b = (unsigned*)take((size_t)GN8 * 4);

    const int RB = (N4 + 255) / 256;   // 1563 blocks per branch-round

    k_init<<<3125, 256, 0, stream>>>(mask, m_a, counts);
    k_pq<<<PQ_BLOCKS, 256, 0, stream>>>(x, Wt, bt, pq);
    k_count<<<(ETOT + 255) / 256, 256, 0, stream>>>(sei + ES, dei + ED, counts);
    k_scan1<<<SCAN_BLOCKS, 256, 0, stream>>>(counts, bsum);
    k_scan2<<<1, 256, 0, stream>>>(bsum, prefix);
    k_scan3<<<SCAN_BLOCKS, 256, 0, stream>>>(counts, prefix, off, cursor);
    k_ewfill<<<(ETOT + 255) / 256, 256, 0, stream>>>(pq,
        sei, sei + ES, dei, dei + ED, sattr, dattr, Wp, bp, Wd, bd, cursor, csr);
    k_round_t<0, 0><<<RB, 256, 0, stream>>>(m_a, m_b, off, csr);
    k_round_t<NNODES, 1><<<RB, 256, 0, stream>>>(m_a, m_b, off, csr);
    k_round_t<0, 2><<<RB, 256, 0, stream>>>(m_b, m_a, off, csr);
    k_round_t<NNODES, 3><<<RB, 256, 0, stream>>>(m_b, m_a, off, csr);
    k_round_final<<<RB, 256, 0, stream>>>(m_a, out, off, csr);
}